// Round 14
// baseline (53.909 us; speedup 1.0000x reference)
//
#include <hip/hip_runtime.h>
#include <math.h>

namespace {

constexpr int B   = 2048;
constexpr int L   = 200;
constexpr int E   = 96;    // 3 * D_FEAT
constexpr int U   = 64;
constexpr int NA  = 36;    // HID_ATT
constexpr int H1  = 200;
constexpr int H2  = 80;
constexpr int RB1 = 4;     // rows per block, gemm1  (512 blocks = 2/CU)
constexpr int RBM = 4;     // rows per block, mlp    (512 blocks = 2/CU)
constexpr int RBF = 4;     // rows per block, final  (512 blocks = 2/CU)
constexpr int NBLK1 = B / RB1;   // 512
constexpr int NBLKM = B / RBM;   // 512
constexpr int NBLKF = B / RBF;   // 512

__device__ __forceinline__ float sigf(float x) {
    return 1.0f / (1.0f + __expf(-x));
}

// DPP partial sums (VALU only, no DS pipe).
template <int CTRL>
__device__ __forceinline__ float dppadd(float x) {
    int v = __builtin_amdgcn_update_dpp(0, __builtin_bit_cast(int, x),
                                        CTRL, 0xf, 0xf, true);
    return x + __builtin_bit_cast(float, v);
}
// sum over each 8-lane group: ^1, ^2, then half-row mirror.
__device__ __forceinline__ float grp8_sum(float p) {
    p = dppadd<0xB1>(p);    // quad_perm ^1
    p = dppadd<0x4E>(p);    // quad_perm ^2
    p = dppadd<0x141>(p);   // row_half_mirror
    return p;
}
__device__ __forceinline__ float grp32_sum(float p) {
    p = grp8_sum(p);
    p = dppadd<0x140>(p);   // row_mirror
    p += __shfl_xor(p, 16);
    return p;
}
__device__ __forceinline__ float wave64_sum(float p) {
    p = grp32_sum(p);
    p += __shfl_xor(p, 32);
    return p;
}

// ---------------------------------------------------------------------------
// K1: one batch row per block. Per-block fold of the linear attention MLP,
// then 32 groups x 8 lanes; lane ln owns features e = 32f + 4ln + {0..3}
// -> 3 float4 gathers per item, 3-DPP score reduce. (validated r13)
// ---------------------------------------------------------------------------
__global__ __launch_bounds__(256) void k_attn(
    const int* __restrict__ user, const int* __restrict__ item,
    const int* __restrict__ rec,
    const float* __restrict__ tu, const float* __restrict__ t1,
    const float* __restrict__ t2, const float* __restrict__ t3,
    const float* __restrict__ w_att1, const float* __restrict__ b_att1,
    const float* __restrict__ w_att2, const float* __restrict__ b_att2,
    float* __restrict__ feat)
{
    __shared__ float s_v[292];
    __shared__ __align__(16) float s_feat[256];
    __shared__ float s_part[32][E];
    __shared__ __align__(16) int4 s_idx4[L];

    const int b = blockIdx.x, t = threadIdx.x;
    const int g = t >> 3, ln = t & 7;

    // ---- fold: s_v[0..95]=v1+v3 | [96..191]=v2-v3 | [192..287]=v4 | [288]=c
    for (int j = t; j < 289; j += 256) {
        float s;
        if (j < 96) {
            s = 0.f;
            #pragma unroll
            for (int k = 0; k < NA; ++k)
                s += w_att2[k] * (w_att1[k * 384 + j] + w_att1[k * 384 + 192 + j]);
        } else if (j < 192) {
            const int e = j - 96; s = 0.f;
            #pragma unroll
            for (int k = 0; k < NA; ++k)
                s += w_att2[k] * (w_att1[k * 384 + 96 + e] - w_att1[k * 384 + 192 + e]);
        } else if (j < 288) {
            const int e = j - 192; s = 0.f;
            #pragma unroll
            for (int k = 0; k < NA; ++k)
                s += w_att2[k] * w_att1[k * 384 + 288 + e];
        } else {
            s = b_att2[0];
            #pragma unroll
            for (int k = 0; k < NA; ++k) s += w_att2[k] * b_att1[k];
        }
        s_v[j] = s;
    }

    // ---- stage idx (padded to int4), q, user emb ---------------------------
    {
        int* si = (int*)s_idx4;
        for (int i = t; i < L * 3; i += 256) {
            const int v = rec[(size_t)b * L * 3 + i];
            si[(i / 3) * 4 + (i % 3)] = v;
        }
    }
    if (t < E) {                          // q = item_emb -> feat[0..95]
        const int f = t >> 5, e = t & 31;
        const float* tab = (f == 0) ? t1 : ((f == 1) ? t2 : t3);
        s_feat[t] = tab[item[b * 3 + f] * 32 + e];
    }
    if (t >= 192) s_feat[t] = tu[(size_t)user[b] * U + (t - 192)];
    __syncthreads();

    // ---- per-lane score weights for features e = 32f + 4ln + c -------------
    float w[12], cb = 0.f;
    #pragma unroll
    for (int f = 0; f < 3; ++f) {
        #pragma unroll
        for (int c = 0; c < 4; ++c) {
            const int e = 32 * f + 4 * ln + c;
            const float q = s_feat[e];
            w[4 * f + c] = s_v[96 + e] + q * s_v[192 + e];
            cb += q * s_v[e];
        }
    }
    cb = grp8_sum(cb) + s_v[288];

    // ---- fused score + browse: items l = g + 32*i, 3 float4 gathers each ---
    float acc[12];
    #pragma unroll
    for (int m = 0; m < 12; ++m) acc[m] = 0.f;
    #pragma unroll
    for (int i = 0; i < 7; ++i) {
        const int l = g + (i << 5);
        if (l < L) {
            const int4 iv = s_idx4[l];
            const float4 u0 = *(const float4*)(t1 + iv.x * 32 + 4 * ln);
            const float4 u1 = *(const float4*)(t2 + iv.y * 32 + 4 * ln);
            const float4 u2 = *(const float4*)(t3 + iv.z * 32 + 4 * ln);
            float p = u0.x * w[0] + u0.y * w[1] + u0.z * w[2]  + u0.w * w[3]
                    + u1.x * w[4] + u1.y * w[5] + u1.z * w[6]  + u1.w * w[7]
                    + u2.x * w[8] + u2.y * w[9] + u2.z * w[10] + u2.w * w[11];
            p = grp8_sum(p);
            const float sc = (iv.x == 0) ? 0.f : (cb + p);
            acc[0] += sc * u0.x; acc[1]  += sc * u0.y;
            acc[2] += sc * u0.z; acc[3]  += sc * u0.w;
            acc[4] += sc * u1.x; acc[5]  += sc * u1.y;
            acc[6] += sc * u1.z; acc[7]  += sc * u1.w;
            acc[8] += sc * u2.x; acc[9]  += sc * u2.y;
            acc[10] += sc * u2.z; acc[11] += sc * u2.w;
        }
    }
    #pragma unroll
    for (int f = 0; f < 3; ++f) {
        #pragma unroll
        for (int c = 0; c < 4; ++c)
            s_part[g][32 * f + 4 * ln + c] = acc[4 * f + c];
    }
    __syncthreads();

    if (t < E) {                          // browse -> feat[96..191]
        float s = 0.f;
        #pragma unroll
        for (int gg = 0; gg < 32; ++gg) s += s_part[gg][t];
        s_feat[96 + t] = s;
    }
    __syncthreads();

    feat[(size_t)b * 256 + t] = s_feat[t];
}

// ---------------------------------------------------------------------------
// K2: y1 = feat @ w1^T + b1. RB1=4 rows/block (grid 512 = 2 blocks/CU for
// w1-stream latency overlap); per-block column partials.
// ---------------------------------------------------------------------------
__global__ __launch_bounds__(256) void k_gemm1(
    const float* __restrict__ feat,
    const float* __restrict__ w1, const float* __restrict__ b1,
    float* __restrict__ y1, float* __restrict__ part1)
{
    __shared__ __align__(16) float s_f[RB1 * 256];
    const int t = threadIdx.x, b0 = blockIdx.x * RB1;

    ((float4*)s_f)[t] = ((const float4*)(feat + (size_t)b0 * 256))[t];
    __syncthreads();

    if (t < H1) {
        const float4* wr = (const float4*)(w1 + t * 256);
        float acc[RB1];
        const float bj = b1[t];
        #pragma unroll
        for (int bb = 0; bb < RB1; ++bb) acc[bb] = bj;
        #pragma unroll 4
        for (int k = 0; k < 64; ++k) {
            const float4 w = wr[k];
            #pragma unroll
            for (int bb = 0; bb < RB1; ++bb) {
                const float4 f = ((const float4*)(s_f + bb * 256))[k];
                acc[bb] += w.x * f.x + w.y * f.y + w.z * f.z + w.w * f.w;
            }
        }
        float s1 = 0.f, s2 = 0.f;
        #pragma unroll
        for (int bb = 0; bb < RB1; ++bb) {
            y1[(size_t)(b0 + bb) * H1 + t] = acc[bb];
            s1 += acc[bb]; s2 += acc[bb] * acc[bb];
        }
        part1[(size_t)blockIdx.x * 400 + t]       = s1;
        part1[(size_t)blockIdx.x * 400 + 200 + t] = s2;
    }
}

// ---------------------------------------------------------------------------
// Stats finalize: one block per column; threads sweep NROWS partial rows
// (grid-stride), LDS tree reduce, write sc/sh.
// ---------------------------------------------------------------------------
template <int NCOL, int STRIDE, int NROWS>
__global__ __launch_bounds__(256) void k_stats(
    const float* __restrict__ part, const float* __restrict__ g,
    const float* __restrict__ be,
    float* __restrict__ sc, float* __restrict__ sh)
{
    __shared__ float rs[256], rq[256];
    const int j = blockIdx.x, t = threadIdx.x;
    float s = 0.f, q = 0.f;
    #pragma unroll
    for (int r = t; r < NROWS; r += 256) {
        s += part[(size_t)r * STRIDE + j];
        q += part[(size_t)r * STRIDE + NCOL + j];
    }
    rs[t] = s; rq[t] = q;
    __syncthreads();
    #pragma unroll
    for (int o = 128; o > 0; o >>= 1) {
        if (t < o) { rs[t] += rs[t + o]; rq[t] += rq[t + o]; }
        __syncthreads();
    }
    if (t == 0) {
        const float mean = rs[0] * (1.f / B);
        float var = (rq[0] - (float)B * mean * mean) * (1.f / (B - 1));
        var = fmaxf(var, 0.f);
        const float a = g[j] * rsqrtf(var + 1e-8f);
        sc[j] = a;
        sh[j] = be[j] - mean * a;
    }
}

// ---------------------------------------------------------------------------
// K3: dice(y1) -> y2 = x @ w2^T + b2. RBM=4 rows/block (grid 512 = 2/CU).
// (validated r12/r13)
// ---------------------------------------------------------------------------
__global__ __launch_bounds__(256) void k_mlp(
    const float* __restrict__ y1,
    const float* __restrict__ sc1, const float* __restrict__ sh1,
    const float* __restrict__ a1,
    const float* __restrict__ w2, const float* __restrict__ b2,
    float* __restrict__ y2, float* __restrict__ part2)
{
    __shared__ float s_c1[H1], s_h1[H1], s_al[H1];
    __shared__ __align__(16) float s_x[RBM][H1];
    __shared__ float s_p1[2][H2], s_p2[2][H2];
    const int t = threadIdx.x, b0 = blockIdx.x * RBM;

    if (t < H1) { s_c1[t] = sc1[t]; s_h1[t] = sh1[t]; s_al[t] = a1[t]; }
    __syncthreads();

    for (int i = t; i < RBM * H1; i += 256) {
        const int j = i % H1;
        const float xn = y1[(size_t)b0 * H1 + i] * s_c1[j] + s_h1[j];
        const float p  = sigf(xn);
        s_x[i / H1][j] = xn * (p + s_al[j] * (1.f - p));
    }
    __syncthreads();

    const int j = t % H2, rr = t / H2;    // rr 0..1 for t<160
    if (t < 160) {
        const float4* wr = (const float4*)(w2 + j * H1);
        const float bj = b2[j];
        float acc0 = bj, acc1 = bj;       // rows rr, rr+2
        #pragma unroll 2
        for (int k = 0; k < H1 / 4; ++k) {
            const float4 w = wr[k];
            const float4 x0 = ((const float4*)s_x[rr])[k];
            const float4 x1 = ((const float4*)s_x[rr + 2])[k];
            acc0 += w.x * x0.x + w.y * x0.y + w.z * x0.z + w.w * x0.w;
            acc1 += w.x * x1.x + w.y * x1.y + w.z * x1.z + w.w * x1.w;
        }
        y2[(size_t)(b0 + rr) * H2 + j]     = acc0;
        y2[(size_t)(b0 + rr + 2) * H2 + j] = acc1;
        s_p1[rr][j] = acc0 + acc1;
        s_p2[rr][j] = acc0 * acc0 + acc1 * acc1;
    }
    __syncthreads();
    if (t < H2) {
        part2[(size_t)blockIdx.x * 160 + t]      = s_p1[0][t] + s_p1[1][t];
        part2[(size_t)blockIdx.x * 160 + 80 + t] = s_p2[0][t] + s_p2[1][t];
    }
}

// ---------------------------------------------------------------------------
// K4: dice(y2), dot w3, sigmoid. RBF=4 rows/block (grid 512 = 2/CU), one
// row per 64-lane wave, wave64 DPP+shfl reduce.
// ---------------------------------------------------------------------------
__global__ __launch_bounds__(256) void k_final(
    const float* __restrict__ y2,
    const float* __restrict__ sc2, const float* __restrict__ sh2,
    const float* __restrict__ a2,
    const float* __restrict__ w3, const float* __restrict__ b3,
    float* __restrict__ out)
{
    __shared__ float s_c[H2], s_s[H2], s_aw[H2], s_w3[H2];
    const int t = threadIdx.x, b0 = blockIdx.x * RBF;
    const int wv = t >> 6, ln = t & 63;

    if (t < H2) {
        s_c[t] = sc2[t]; s_s[t] = sh2[t];
        s_aw[t] = a2[t]; s_w3[t] = w3[t];
    }
    __syncthreads();

    const int r = b0 + wv;
    float acc;
    {
        const float xn = y2[(size_t)r * H2 + ln] * s_c[ln] + s_s[ln];
        const float p  = sigf(xn);
        acc = xn * (p + s_aw[ln] * (1.f - p)) * s_w3[ln];
    }
    if (ln < H2 - 64) {
        const int j = 64 + ln;
        const float xn = y2[(size_t)r * H2 + j] * s_c[j] + s_s[j];
        const float p  = sigf(xn);
        acc += xn * (p + s_aw[j] * (1.f - p)) * s_w3[j];
    }
    acc = wave64_sum(acc);
    if (ln == 0) out[r] = sigf(acc + b3[0]);
}

} // namespace

extern "C" void kernel_launch(void* const* d_in, const int* in_sizes, int n_in,
                              void* d_out, int out_size, void* d_ws, size_t ws_size,
                              hipStream_t stream) {
    const int*   user   = (const int*)d_in[0];
    const int*   item   = (const int*)d_in[1];
    const int*   rec    = (const int*)d_in[2];
    const float* tu     = (const float*)d_in[3];
    const float* t1     = (const float*)d_in[4];
    const float* t2     = (const float*)d_in[5];
    const float* t3     = (const float*)d_in[6];
    const float* w_att1 = (const float*)d_in[7];
    const float* b_att1 = (const float*)d_in[8];
    const float* w_att2 = (const float*)d_in[9];
    const float* b_att2 = (const float*)d_in[10];
    const float* w1     = (const float*)d_in[11];
    const float* b1     = (const float*)d_in[12];
    const float* a1     = (const float*)d_in[13];
    const float* g1     = (const float*)d_in[14];
    const float* be1    = (const float*)d_in[15];
    const float* w2     = (const float*)d_in[16];
    const float* b2     = (const float*)d_in[17];
    const float* a2     = (const float*)d_in[18];
    const float* g2     = (const float*)d_in[19];
    const float* be2    = (const float*)d_in[20];
    const float* w3     = (const float*)d_in[21];
    const float* b3     = (const float*)d_in[22];
    float* out = (float*)d_out;

    float* ws    = (float*)d_ws;
    float* part1 = ws;                            // 512*400
    float* part2 = part1 + (size_t)NBLK1 * 400;   // 512*160
    float* sc1   = part2 + (size_t)NBLKM * 160;   // 256 (200 used)
    float* sh1   = sc1 + 256;                     // 256
    float* sc2   = sh1 + 256;                     // 128 (80 used)
    float* sh2   = sc2 + 128;                     // 128
    float* feat  = sh2 + 128;                     // B*256
    float* y1    = feat + (size_t)B * 256;        // B*H1
    float* y2    = y1 + (size_t)B * H1;           // B*H2

    hipLaunchKernelGGL(k_attn,  dim3(B),     dim3(256), 0, stream,
                       user, item, rec, tu, t1, t2, t3,
                       w_att1, b_att1, w_att2, b_att2, feat);
    hipLaunchKernelGGL(k_gemm1, dim3(NBLK1), dim3(256), 0, stream,
                       feat, w1, b1, y1, part1);
    hipLaunchKernelGGL((k_stats<H1, 400, NBLK1>), dim3(H1), dim3(256), 0, stream,
                       part1, g1, be1, sc1, sh1);
    hipLaunchKernelGGL(k_mlp,   dim3(NBLKM), dim3(256), 0, stream,
                       y1, sc1, sh1, a1, w2, b2, y2, part2);
    hipLaunchKernelGGL((k_stats<H2, 160, NBLKM>), dim3(H2), dim3(256), 0, stream,
                       part2, g2, be2, sc2, sh2);
    hipLaunchKernelGGL(k_final, dim3(NBLKF), dim3(256), 0, stream,
                       y2, sc2, sh2, a2, w3, b3, out);
}

// Round 15
// 49.347 us; speedup vs baseline: 1.0924x; 1.0924x over previous
//
#include <hip/hip_runtime.h>
#include <math.h>

namespace {

constexpr int B   = 2048;
constexpr int L   = 200;
constexpr int E   = 96;    // 3 * D_FEAT
constexpr int U   = 64;
constexpr int NA  = 36;    // HID_ATT
constexpr int H1  = 200;
constexpr int H2  = 80;
constexpr int RB  = 8;     // rows per block, gemm1 / final (w1 is 200KB: keep reuse high)
constexpr int RBM = 4;     // rows per block, mlp (w2 is 64KB: occupancy wins)
constexpr int NBLK  = B / RB;    // 256
constexpr int NBLKM = B / RBM;   // 512

__device__ __forceinline__ float sigf(float x) {
    return 1.0f / (1.0f + __expf(-x));
}

// DPP partial sums (VALU only, no DS pipe).
template <int CTRL>
__device__ __forceinline__ float dppadd(float x) {
    int v = __builtin_amdgcn_update_dpp(0, __builtin_bit_cast(int, x),
                                        CTRL, 0xf, 0xf, true);
    return x + __builtin_bit_cast(float, v);
}
// sum over each 8-lane group: ^1, ^2, then half-row mirror (i -> 7-i).
__device__ __forceinline__ float grp8_sum(float p) {
    p = dppadd<0xB1>(p);    // quad_perm ^1
    p = dppadd<0x4E>(p);    // quad_perm ^2
    p = dppadd<0x141>(p);   // row_half_mirror: other quad of the 8
    return p;
}
__device__ __forceinline__ float grp32_sum(float p) {
    p = grp8_sum(p);
    p = dppadd<0x140>(p);   // row_mirror: other 8 of the 16
    p += __shfl_xor(p, 16);
    return p;
}

// ---------------------------------------------------------------------------
// K1: one batch row per block. Per-block fold of the linear attention MLP,
// then 32 groups x 8 lanes; lane ln owns features e = 32f + 4ln + {0..3}
// -> each item costs 3 float4 gathers (one full 128B table row per group),
// score reduce = 3 DPP ops. Per wave-iter: 3 VMEM instrs serve 8 items.
// (validated r13: 49.05us total)
// ---------------------------------------------------------------------------
__global__ __launch_bounds__(256) void k_attn(
    const int* __restrict__ user, const int* __restrict__ item,
    const int* __restrict__ rec,
    const float* __restrict__ tu, const float* __restrict__ t1,
    const float* __restrict__ t2, const float* __restrict__ t3,
    const float* __restrict__ w_att1, const float* __restrict__ b_att1,
    const float* __restrict__ w_att2, const float* __restrict__ b_att2,
    float* __restrict__ feat)
{
    __shared__ float s_v[292];
    __shared__ __align__(16) float s_feat[256];
    __shared__ float s_part[32][E];
    __shared__ __align__(16) int4 s_idx4[L];

    const int b = blockIdx.x, t = threadIdx.x;
    const int g = t >> 3, ln = t & 7;

    // ---- fold: s_v[0..95]=v1+v3 | [96..191]=v2-v3 | [192..287]=v4 | [288]=c
    for (int j = t; j < 289; j += 256) {
        float s;
        if (j < 96) {
            s = 0.f;
            #pragma unroll
            for (int k = 0; k < NA; ++k)
                s += w_att2[k] * (w_att1[k * 384 + j] + w_att1[k * 384 + 192 + j]);
        } else if (j < 192) {
            const int e = j - 96; s = 0.f;
            #pragma unroll
            for (int k = 0; k < NA; ++k)
                s += w_att2[k] * (w_att1[k * 384 + 96 + e] - w_att1[k * 384 + 192 + e]);
        } else if (j < 288) {
            const int e = j - 192; s = 0.f;
            #pragma unroll
            for (int k = 0; k < NA; ++k)
                s += w_att2[k] * w_att1[k * 384 + 288 + e];
        } else {
            s = b_att2[0];
            #pragma unroll
            for (int k = 0; k < NA; ++k) s += w_att2[k] * b_att1[k];
        }
        s_v[j] = s;
    }

    // ---- stage idx (padded to int4), q, user emb ---------------------------
    {
        int* si = (int*)s_idx4;
        for (int i = t; i < L * 3; i += 256) {
            const int v = rec[(size_t)b * L * 3 + i];
            si[(i / 3) * 4 + (i % 3)] = v;
        }
    }
    if (t < E) {                          // q = item_emb -> feat[0..95]
        const int f = t >> 5, e = t & 31;
        const float* tab = (f == 0) ? t1 : ((f == 1) ? t2 : t3);
        s_feat[t] = tab[item[b * 3 + f] * 32 + e];
    }
    if (t >= 192) s_feat[t] = tu[(size_t)user[b] * U + (t - 192)];
    __syncthreads();

    // ---- per-lane score weights for features e = 32f + 4ln + c -------------
    float w[12], cb = 0.f;
    #pragma unroll
    for (int f = 0; f < 3; ++f) {
        #pragma unroll
        for (int c = 0; c < 4; ++c) {
            const int e = 32 * f + 4 * ln + c;
            const float q = s_feat[e];
            w[4 * f + c] = s_v[96 + e] + q * s_v[192 + e];
            cb += q * s_v[e];
        }
    }
    cb = grp8_sum(cb) + s_v[288];

    // ---- fused score + browse: items l = g + 32*i, 3 float4 gathers each ---
    float acc[12];
    #pragma unroll
    for (int m = 0; m < 12; ++m) acc[m] = 0.f;
    #pragma unroll
    for (int i = 0; i < 7; ++i) {
        const int l = g + (i << 5);
        if (l < L) {
            const int4 iv = s_idx4[l];
            const float4 u0 = *(const float4*)(t1 + iv.x * 32 + 4 * ln);
            const float4 u1 = *(const float4*)(t2 + iv.y * 32 + 4 * ln);
            const float4 u2 = *(const float4*)(t3 + iv.z * 32 + 4 * ln);
            float p = u0.x * w[0] + u0.y * w[1] + u0.z * w[2]  + u0.w * w[3]
                    + u1.x * w[4] + u1.y * w[5] + u1.z * w[6]  + u1.w * w[7]
                    + u2.x * w[8] + u2.y * w[9] + u2.z * w[10] + u2.w * w[11];
            p = grp8_sum(p);
            const float sc = (iv.x == 0) ? 0.f : (cb + p);
            acc[0] += sc * u0.x; acc[1]  += sc * u0.y;
            acc[2] += sc * u0.z; acc[3]  += sc * u0.w;
            acc[4] += sc * u1.x; acc[5]  += sc * u1.y;
            acc[6] += sc * u1.z; acc[7]  += sc * u1.w;
            acc[8] += sc * u2.x; acc[9]  += sc * u2.y;
            acc[10] += sc * u2.z; acc[11] += sc * u2.w;
        }
    }
    #pragma unroll
    for (int f = 0; f < 3; ++f) {
        #pragma unroll
        for (int c = 0; c < 4; ++c)
            s_part[g][32 * f + 4 * ln + c] = acc[4 * f + c];
    }
    __syncthreads();

    if (t < E) {                          // browse -> feat[96..191]
        float s = 0.f;
        #pragma unroll
        for (int gg = 0; gg < 32; ++gg) s += s_part[gg][t];
        s_feat[96 + t] = s;
    }
    __syncthreads();

    feat[(size_t)b * 256 + t] = s_feat[t];
}

// ---------------------------------------------------------------------------
// K2: y1 = feat @ w1^T + b1 (8 rows/block: w1 is 200KB so reuse beats
// occupancy -- r14 measured RB=4 as -4.9us); per-block column partials.
// ---------------------------------------------------------------------------
__global__ __launch_bounds__(256) void k_gemm1(
    const float* __restrict__ feat,
    const float* __restrict__ w1, const float* __restrict__ b1,
    float* __restrict__ y1, float* __restrict__ part1)
{
    __shared__ __align__(16) float s_f[RB * 256];
    const int t = threadIdx.x, b0 = blockIdx.x * RB;

    const float4* src = (const float4*)(feat + (size_t)b0 * 256);
    float4* dst = (float4*)s_f;
    dst[t] = src[t];
    dst[t + 256] = src[t + 256];
    __syncthreads();

    if (t < H1) {
        const float4* wr = (const float4*)(w1 + t * 256);
        float acc[RB];
        const float bj = b1[t];
        #pragma unroll
        for (int bb = 0; bb < RB; ++bb) acc[bb] = bj;
        #pragma unroll 4
        for (int k = 0; k < 64; ++k) {
            const float4 w = wr[k];
            #pragma unroll
            for (int bb = 0; bb < RB; ++bb) {
                const float4 f = ((const float4*)(s_f + bb * 256))[k];
                acc[bb] += w.x * f.x + w.y * f.y + w.z * f.z + w.w * f.w;
            }
        }
        float s1 = 0.f, s2 = 0.f;
        #pragma unroll
        for (int bb = 0; bb < RB; ++bb) {
            y1[(size_t)(b0 + bb) * H1 + t] = acc[bb];
            s1 += acc[bb]; s2 += acc[bb] * acc[bb];
        }
        part1[(size_t)blockIdx.x * 400 + t]       = s1;
        part1[(size_t)blockIdx.x * 400 + 200 + t] = s2;
    }
}

// ---------------------------------------------------------------------------
// Stats finalize: one block per column; threads sweep NROWS partial rows
// (grid-stride), LDS tree reduce, write sc/sh.
// ---------------------------------------------------------------------------
template <int NCOL, int STRIDE, int NROWS>
__global__ __launch_bounds__(256) void k_stats(
    const float* __restrict__ part, const float* __restrict__ g,
    const float* __restrict__ be,
    float* __restrict__ sc, float* __restrict__ sh)
{
    __shared__ float rs[256], rq[256];
    const int j = blockIdx.x, t = threadIdx.x;
    float s = 0.f, q = 0.f;
    #pragma unroll
    for (int r = t; r < NROWS; r += 256) {
        s += part[(size_t)r * STRIDE + j];
        q += part[(size_t)r * STRIDE + NCOL + j];
    }
    rs[t] = s; rq[t] = q;
    __syncthreads();
    #pragma unroll
    for (int o = 128; o > 0; o >>= 1) {
        if (t < o) { rs[t] += rs[t + o]; rq[t] += rq[t + o]; }
        __syncthreads();
    }
    if (t == 0) {
        const float mean = rs[0] * (1.f / B);
        float var = (rq[0] - (float)B * mean * mean) * (1.f / (B - 1));
        var = fmaxf(var, 0.f);
        const float a = g[j] * rsqrtf(var + 1e-8f);
        sc[j] = a;
        sh[j] = be[j] - mean * a;
    }
}

// ---------------------------------------------------------------------------
// K3: dice(y1) -> y2 = x @ w2^T + b2. RBM=4 rows/block (grid 512 = 2/CU:
// w2 is only 64KB so the re-stream is cheap and occupancy wins -- r12).
// ---------------------------------------------------------------------------
__global__ __launch_bounds__(256) void k_mlp(
    const float* __restrict__ y1,
    const float* __restrict__ sc1, const float* __restrict__ sh1,
    const float* __restrict__ a1,
    const float* __restrict__ w2, const float* __restrict__ b2,
    float* __restrict__ y2, float* __restrict__ part2)
{
    __shared__ float s_c1[H1], s_h1[H1], s_al[H1];
    __shared__ __align__(16) float s_x[RBM][H1];
    __shared__ float s_p1[2][H2], s_p2[2][H2];
    const int t = threadIdx.x, b0 = blockIdx.x * RBM;

    if (t < H1) { s_c1[t] = sc1[t]; s_h1[t] = sh1[t]; s_al[t] = a1[t]; }
    __syncthreads();

    for (int i = t; i < RBM * H1; i += 256) {
        const int j = i % H1;
        const float xn = y1[(size_t)b0 * H1 + i] * s_c1[j] + s_h1[j];
        const float p  = sigf(xn);
        s_x[i / H1][j] = xn * (p + s_al[j] * (1.f - p));
    }
    __syncthreads();

    const int j = t % H2, rr = t / H2;    // rr 0..1 for t<160
    if (t < 160) {
        const float4* wr = (const float4*)(w2 + j * H1);
        const float bj = b2[j];
        float acc0 = bj, acc1 = bj;       // rows rr, rr+2
        #pragma unroll 2
        for (int k = 0; k < H1 / 4; ++k) {
            const float4 w = wr[k];
            const float4 x0 = ((const float4*)s_x[rr])[k];
            const float4 x1 = ((const float4*)s_x[rr + 2])[k];
            acc0 += w.x * x0.x + w.y * x0.y + w.z * x0.z + w.w * x0.w;
            acc1 += w.x * x1.x + w.y * x1.y + w.z * x1.z + w.w * x1.w;
        }
        y2[(size_t)(b0 + rr) * H2 + j]     = acc0;
        y2[(size_t)(b0 + rr + 2) * H2 + j] = acc1;
        s_p1[rr][j] = acc0 + acc1;
        s_p2[rr][j] = acc0 * acc0 + acc1 * acc1;
    }
    __syncthreads();
    if (t < H2) {
        part2[(size_t)blockIdx.x * 160 + t]      = s_p1[0][t] + s_p1[1][t];
        part2[(size_t)blockIdx.x * 160 + 80 + t] = s_p2[0][t] + s_p2[1][t];
    }
}

// ---------------------------------------------------------------------------
// K4: dice(y2), dot w3, sigmoid. 8 rows/block, 32 lanes per row.
// ---------------------------------------------------------------------------
__global__ __launch_bounds__(256) void k_final(
    const float* __restrict__ y2,
    const float* __restrict__ sc2, const float* __restrict__ sh2,
    const float* __restrict__ a2,
    const float* __restrict__ w3, const float* __restrict__ b3,
    float* __restrict__ out)
{
    __shared__ float s_c[H2], s_s[H2], s_aw[H2], s_w3[H2];
    const int t = threadIdx.x, b0 = blockIdx.x * RB;
    const int g = t >> 5, lane = t & 31;

    if (t < H2) {
        s_c[t] = sc2[t]; s_s[t] = sh2[t];
        s_aw[t] = a2[t]; s_w3[t] = w3[t];
    }
    __syncthreads();

    const int r = b0 + g;
    float acc = 0.f;
    #pragma unroll
    for (int jj = 0; jj < 3; ++jj) {
        const int j = lane + jj * 32;
        if (j < H2) {
            const float xn = y2[(size_t)r * H2 + j] * s_c[j] + s_s[j];
            const float p  = sigf(xn);
            acc += xn * (p + s_aw[j] * (1.f - p)) * s_w3[j];
        }
    }
    acc = grp32_sum(acc);
    if (lane == 0) out[r] = sigf(acc + b3[0]);
}

} // namespace

extern "C" void kernel_launch(void* const* d_in, const int* in_sizes, int n_in,
                              void* d_out, int out_size, void* d_ws, size_t ws_size,
                              hipStream_t stream) {
    const int*   user   = (const int*)d_in[0];
    const int*   item   = (const int*)d_in[1];
    const int*   rec    = (const int*)d_in[2];
    const float* tu     = (const float*)d_in[3];
    const float* t1     = (const float*)d_in[4];
    const float* t2     = (const float*)d_in[5];
    const float* t3     = (const float*)d_in[6];
    const float* w_att1 = (const float*)d_in[7];
    const float* b_att1 = (const float*)d_in[8];
    const float* w_att2 = (const float*)d_in[9];
    const float* b_att2 = (const float*)d_in[10];
    const float* w1     = (const float*)d_in[11];
    const float* b1     = (const float*)d_in[12];
    const float* a1     = (const float*)d_in[13];
    const float* g1     = (const float*)d_in[14];
    const float* be1    = (const float*)d_in[15];
    const float* w2     = (const float*)d_in[16];
    const float* b2     = (const float*)d_in[17];
    const float* a2     = (const float*)d_in[18];
    const float* g2     = (const float*)d_in[19];
    const float* be2    = (const float*)d_in[20];
    const float* w3     = (const float*)d_in[21];
    const float* b3     = (const float*)d_in[22];
    float* out = (float*)d_out;

    float* ws    = (float*)d_ws;
    float* part1 = ws;                            // 256*400
    float* part2 = part1 + (size_t)NBLK * 400;    // 512*160
    float* sc1   = part2 + (size_t)NBLKM * 160;   // 256 (200 used)
    float* sh1   = sc1 + 256;                     // 256
    float* sc2   = sh1 + 256;                     // 128 (80 used)
    float* sh2   = sc2 + 128;                     // 128
    float* feat  = sh2 + 128;                     // B*256
    float* y1    = feat + (size_t)B * 256;        // B*H1
    float* y2    = y1 + (size_t)B * H1;           // B*H2

    hipLaunchKernelGGL(k_attn,  dim3(B),     dim3(256), 0, stream,
                       user, item, rec, tu, t1, t2, t3,
                       w_att1, b_att1, w_att2, b_att2, feat);
    hipLaunchKernelGGL(k_gemm1, dim3(NBLK),  dim3(256), 0, stream,
                       feat, w1, b1, y1, part1);
    hipLaunchKernelGGL((k_stats<H1, 400, NBLK>), dim3(H1), dim3(256), 0, stream,
                       part1, g1, be1, sc1, sh1);
    hipLaunchKernelGGL(k_mlp,   dim3(NBLKM), dim3(256), 0, stream,
                       y1, sc1, sh1, a1, w2, b2, y2, part2);
    hipLaunchKernelGGL((k_stats<H2, 160, NBLKM>), dim3(H2), dim3(256), 0, stream,
                       part2, g2, be2, sc2, sh2);
    hipLaunchKernelGGL(k_final, dim3(NBLK),  dim3(256), 0, stream,
                       y2, sc2, sh2, a2, w3, b3, out);
}